// Round 1
// 1488.060 us; speedup vs baseline: 1.6238x; 1.6238x over previous
//
#include <hip/hip_runtime.h>
#include <hip/hip_bf16.h>

#define HIDDEN 128
#define NRBF 64

typedef __attribute__((ext_vector_type(8))) short short8;   // 8 bf16 (4 VGPRs)
typedef __attribute__((ext_vector_type(4))) float float4v;  // 4 fp32 acc

#define ATTR_LD 72   // bf16 stride for attr tile (64+8): 16B-aligned rows
#define H_LD 136     // bf16 stride for H tile (128+8): 16B-aligned rows
#define MSG_LD 132   // bf16 stride for msg tile: quad rows land on distinct bank groups

static __device__ __forceinline__ float silu(float v) {
    return v / (1.0f + __expf(-v));
}

static __device__ __forceinline__ short f2bf(float v) {
    __hip_bfloat16 b = __float2bfloat16(v);
    return *reinterpret_cast<short*>(&b);
}

// ---------------------------------------------------------------------------
// Weights -> bf16, transposed to [n][k] so MFMA B-fragments are contiguous.
// ---------------------------------------------------------------------------
__global__ __launch_bounds__(256) void conv_weights(
    const float* __restrict__ w1, const float* __restrict__ w2,
    short* __restrict__ w1f, short* __restrict__ w2f) {
    int idx = blockIdx.x * 256 + threadIdx.x;
    if (idx < HIDDEN * NRBF) {           // w1f[n][k] = w1[k][n], 128x64
        int n = idx >> 6, k = idx & 63;
        w1f[idx] = f2bf(w1[k * HIDDEN + n]);
    }
    if (idx < HIDDEN * HIDDEN) {         // w2f[n][k] = w2[k][n], 128x128
        int n = idx >> 7, k = idx & 127;
        w2f[idx] = f2bf(w2[k * HIDDEN + n]);
    }
}

// ---------------------------------------------------------------------------
// gemm32: out[n] = in[n] @ w   (fp32, 32 nodes per 256-thread block)
// Rows staged in LDS (broadcast reads); weight loads coalesced, shared by
// 32 nodes -> 32x less L2 weight traffic than one-node-per-block.
// ---------------------------------------------------------------------------
__global__ __launch_bounds__(256) void gemm32(
    const float* __restrict__ in, const float* __restrict__ w,
    float* __restrict__ out, int N) {
    __shared__ float rows[32][HIDDEN];
    const int n0 = blockIdx.x * 32;
    const int tid = threadIdx.x;

    const float4* ag = (const float4*)(in + (size_t)n0 * HIDDEN);
    float4 v[4];
#pragma unroll
    for (int i = 0; i < 4; ++i) {
        int fi = i * 256 + tid;                 // [0,1024) float4 index
        int nr = n0 + (fi >> 5);
        v[i] = (nr < N) ? ag[fi] : make_float4(0.f, 0.f, 0.f, 0.f);
    }
#pragma unroll
    for (int i = 0; i < 4; ++i) {
        int fi = i * 256 + tid;
        ((float4*)rows)[fi] = v[i];
    }
    __syncthreads();

    const int f = tid & 127;
    const int ng = tid >> 7;                    // node group (0 or 1)
    float acc[16];
#pragma unroll
    for (int j = 0; j < 16; ++j) acc[j] = 0.0f;

    for (int k4 = 0; k4 < HIDDEN / 4; ++k4) {
        const float* wp = w + k4 * 4 * HIDDEN + f;
        float w0 = wp[0], w1 = wp[HIDDEN], w2 = wp[2 * HIDDEN], w3 = wp[3 * HIDDEN];
#pragma unroll
        for (int j = 0; j < 16; ++j) {
            float4 r = *(const float4*)&rows[ng * 16 + j][k4 * 4];
            acc[j] += r.x * w0 + r.y * w1 + r.z * w2 + r.w * w3;
        }
    }
#pragma unroll
    for (int j = 0; j < 16; ++j) {
        int n = n0 + ng * 16 + j;
        if (n < N) out[(size_t)n * HIDDEN + f] = acc[j];
    }
}

// ---------------------------------------------------------------------------
// CSR build: histogram, hierarchical scan (3 small kernels), ticket fill.
// ---------------------------------------------------------------------------
__global__ void hist_kernel(const int* __restrict__ dst, int* __restrict__ counts, int E) {
    int e = blockIdx.x * 256 + threadIdx.x;
    if (e < E) atomicAdd(&counts[dst[e]], 1);
}

__global__ __launch_bounds__(256) void scan_part1(
    const int* __restrict__ counts, int* __restrict__ bsums, int n) {
    int base = blockIdx.x * 1024;
    int t = threadIdx.x;
    int s = 0;
#pragma unroll
    for (int j = 0; j < 4; ++j) {
        int i = base + t * 4 + j;
        if (i < n) s += counts[i];
    }
    for (int off = 32; off; off >>= 1) s += __shfl_down(s, off, 64);
    __shared__ int wsum[4];
    if ((t & 63) == 0) wsum[t >> 6] = s;
    __syncthreads();
    if (t == 0) bsums[blockIdx.x] = wsum[0] + wsum[1] + wsum[2] + wsum[3];
}

__global__ __launch_bounds__(1024) void scan_part2(
    int* __restrict__ bsums, int nb, int* __restrict__ off_total) {
    __shared__ int sd[1024];
    int t = threadIdx.x;
    int v = (t < nb) ? bsums[t] : 0;
    sd[t] = v;
    __syncthreads();
    for (int s = 1; s < 1024; s <<= 1) {
        int u = (t >= s) ? sd[t - s] : 0;
        __syncthreads();
        sd[t] += u;
        __syncthreads();
    }
    if (t < nb) bsums[t] = sd[t] - v;  // exclusive
    if (t == 1023) *off_total = sd[1023];
}

__global__ __launch_bounds__(256) void scan_part3(
    const int* __restrict__ counts, const int* __restrict__ bsums,
    int* __restrict__ off, int* __restrict__ cursor, int n) {
    int base = blockIdx.x * 1024;
    int t = threadIdx.x;
    int i0 = base + t * 4;
    int v[4];
#pragma unroll
    for (int j = 0; j < 4; ++j) v[j] = (i0 + j < n) ? counts[i0 + j] : 0;
    int tsum = v[0] + v[1] + v[2] + v[3];
    int incl = tsum;
    for (int d = 1; d < 64; d <<= 1) {
        int u = __shfl_up(incl, d, 64);
        if ((t & 63) >= d) incl += u;
    }
    __shared__ int wtot[4];
    if ((t & 63) == 63) wtot[t >> 6] = incl;
    __syncthreads();
    int woff = 0;
    for (int w = 0; w < (t >> 6); ++w) woff += wtot[w];
    int run = bsums[blockIdx.x] + woff + (incl - tsum);
#pragma unroll
    for (int j = 0; j < 4; ++j) {
        if (i0 + j < n) {
            off[i0 + j] = run;
            cursor[i0 + j] = run;
            run += v[j];
        }
    }
}

__global__ void fill_kernel(const int* __restrict__ dst, int* __restrict__ cursor,
                            int* __restrict__ csr, int E) {
    int e = blockIdx.x * 256 + threadIdx.x;
    if (e < E) {
        int pos = atomicAdd(&cursor[dst[e]], 1);
        csr[pos] = e;
    }
}

// ---------------------------------------------------------------------------
// Fused MFMA msg kernel + segmented reduction. One 256-thread block (4 waves)
// per 128 CSR positions.
//   GEMM1: H = silu(attr @ w1 + b1)   [128x64]@[64x128], K-steps=2
//   GEMM2: W = H @ w2 + b2            [128x128]@[128x128], K-steps=4
//   msg[row][f] = bf16( xf[src][f] * W * C )  -> LDS tile
//   segmented sum over dst (CSR order is dst-sorted) -> atomicAdd into agg.
// LDS union: attr tile (18.4 KB) / H tile (34.8 KB) / msg tile (33.8 KB)
// alias the same region (each dead before the next is written) -> 36.4 KB
// total -> 4 blocks/CU (was 3 at 54 KB).
// ---------------------------------------------------------------------------
__global__ __launch_bounds__(256, 4) void msg_mfma(
    const int* __restrict__ csr, const int* __restrict__ src,
    const int* __restrict__ dstp,
    const float* __restrict__ ew, const float* __restrict__ attr,
    const short* __restrict__ w1f, const float* __restrict__ b1,
    const short* __restrict__ w2f, const float* __restrict__ b2,
    const float* __restrict__ xf, float* __restrict__ agg, int E) {
    __shared__ __align__(16) short uni[128 * H_LD];  // 34,816 B union
    short* attr_s = uni;   // stride ATTR_LD, live: stage -> GEMM1
    short* h_s    = uni;   // stride H_LD,    live: h-write -> GEMM2
    short* msg_s  = uni;   // stride MSG_LD,  live: msg-write -> reduce
    __shared__ int srcs[128];
    __shared__ int dstn[128];
    __shared__ float Cc[128];

    const int p0 = blockIdx.x * 128;
    const int tid = threadIdx.x;
    const int wave = tid >> 6;
    const int lane = tid & 63;
    const int quad = lane >> 4;
    const int lc = lane & 15;
    const int nbase = wave * 32;

    // ---- stage: per-edge metadata + attr rows (fp32 -> bf16) ----
    {
        int row = tid >> 1;
        int half = tid & 1;
        int p = p0 + row;
        int eid = (p < E) ? csr[p] : 0;
        if (half == 0) {
            srcs[row] = src[eid];
            dstn[row] = (p < E) ? dstp[eid] : -1;
            float w = ew[eid];
            float C = 0.5f * (__cosf(w * 0.62831853071795865f) + 1.0f);
            if (w >= 5.0f) C = 0.0f;
            Cc[row] = C;
        }
        const float4* ap = (const float4*)(attr + (size_t)eid * NRBF + half * 32);
        short* dp = attr_s + row * ATTR_LD + half * 32;
#pragma unroll
        for (int i = 0; i < 8; ++i) {
            float4 v = ap[i];
            short4 s4;
            s4.x = f2bf(v.x); s4.y = f2bf(v.y); s4.z = f2bf(v.z); s4.w = f2bf(v.w);
            *(short4*)(dp + i * 4) = s4;
        }
    }
    __syncthreads();

    // ---- GEMM1: H = attr @ w1 ----
    float4v acc[8][2];
#pragma unroll
    for (int mt = 0; mt < 8; ++mt)
#pragma unroll
        for (int nt = 0; nt < 2; ++nt) acc[mt][nt] = (float4v){0.f, 0.f, 0.f, 0.f};

    short8 bf1[2][2];  // [kk][nt]
#pragma unroll
    for (int kk = 0; kk < 2; ++kk)
#pragma unroll
        for (int nt = 0; nt < 2; ++nt)
            bf1[kk][nt] = *(const short8*)(w1f + (nbase + nt * 16 + lc) * NRBF + kk * 32 + quad * 8);

#pragma unroll
    for (int kk = 0; kk < 2; ++kk) {
#pragma unroll
        for (int mt = 0; mt < 8; ++mt) {
            short8 af = *(const short8*)(attr_s + (mt * 16 + lc) * ATTR_LD + kk * 32 + quad * 8);
            acc[mt][0] = __builtin_amdgcn_mfma_f32_16x16x32_bf16(af, bf1[kk][0], acc[mt][0], 0, 0, 0);
            acc[mt][1] = __builtin_amdgcn_mfma_f32_16x16x32_bf16(af, bf1[kk][1], acc[mt][1], 0, 0, 0);
        }
    }
    __syncthreads();   // all attr reads done before h overwrites the union

    // ---- bias + silu -> h_s (bf16, A-fragment-friendly [edge][k]) ----
#pragma unroll
    for (int nt = 0; nt < 2; ++nt) {
        int col = nbase + nt * 16 + lc;
        float bb = b1[col];
#pragma unroll
        for (int mt = 0; mt < 8; ++mt) {
            float4v a = acc[mt][nt];
#pragma unroll
            for (int r = 0; r < 4; ++r) {
                int row = mt * 16 + quad * 4 + r;
                h_s[row * H_LD + col] = f2bf(silu(a[r] + bb));
            }
        }
    }
    __syncthreads();

    // ---- GEMM2: W = H @ w2 ----
    float4v acc2[8][2];
#pragma unroll
    for (int mt = 0; mt < 8; ++mt)
#pragma unroll
        for (int nt = 0; nt < 2; ++nt) acc2[mt][nt] = (float4v){0.f, 0.f, 0.f, 0.f};

#pragma unroll
    for (int kk = 0; kk < 4; ++kk) {
        short8 bb0 = *(const short8*)(w2f + (nbase + 0 * 16 + lc) * HIDDEN + kk * 32 + quad * 8);
        short8 bb1 = *(const short8*)(w2f + (nbase + 1 * 16 + lc) * HIDDEN + kk * 32 + quad * 8);
#pragma unroll
        for (int mt = 0; mt < 8; ++mt) {
            short8 af = *(const short8*)(h_s + (mt * 16 + lc) * H_LD + kk * 32 + quad * 8);
            acc2[mt][0] = __builtin_amdgcn_mfma_f32_16x16x32_bf16(af, bb0, acc2[mt][0], 0, 0, 0);
            acc2[mt][1] = __builtin_amdgcn_mfma_f32_16x16x32_bf16(af, bb1, acc2[mt][1], 0, 0, 0);
        }
    }

    // ---- in-place transform: acc2 <- msg value = (acc2+b2)*C*xf[src] ----
#pragma unroll
    for (int nt = 0; nt < 2; ++nt) {
        int f = nbase + nt * 16 + lc;
        float bb = b2[f];
#pragma unroll
        for (int mt = 0; mt < 8; ++mt) {
#pragma unroll
            for (int r = 0; r < 4; ++r) {
                int row = mt * 16 + quad * 4 + r;
                int p = p0 + row;
                float v = 0.0f;
                if (p < E) {
                    float Wv = (acc2[mt][nt][r] + bb) * Cc[row];
                    float xv = xf[(size_t)srcs[row] * HIDDEN + f];
                    v = xv * Wv;
                }
                acc2[mt][nt][r] = v;
            }
        }
    }
    __syncthreads();   // all h reads done before msg overwrites the union

    // ---- write msg tile (bf16, matches old global-msg rounding) ----
#pragma unroll
    for (int nt = 0; nt < 2; ++nt) {
        int f = nbase + nt * 16 + lc;
#pragma unroll
        for (int mt = 0; mt < 8; ++mt) {
#pragma unroll
            for (int r = 0; r < 4; ++r) {
                int row = mt * 16 + quad * 4 + r;
                msg_s[row * MSG_LD + f] = f2bf(acc2[mt][nt][r]);
            }
        }
    }
    __syncthreads();

    // ---- segmented sum over dst (non-decreasing in CSR order) ----
    {
        int f = tid & 127;
        int half = tid >> 7;
        int r0 = half * 64;
        float s = 0.0f;
        int cur = dstn[r0];
        for (int r = r0; r < r0 + 64; ++r) {
            int d = dstn[r];
            if (d != cur) {
                if (cur >= 0) atomicAdd(&agg[(size_t)cur * HIDDEN + f], s);
                s = 0.0f;
                cur = d;
            }
            s += __bfloat162float(*(const __hip_bfloat16*)&msg_s[r * MSG_LD + f]);
        }
        if (cur >= 0) atomicAdd(&agg[(size_t)cur * HIDDEN + f], s);
    }
}

// ---------------------------------------------------------------------------
// tail32: agg/deg -> lin2+b -> silu -> lin+b  (32 nodes per 256-thread block)
// ---------------------------------------------------------------------------
__global__ __launch_bounds__(256) void tail32(
    const int* __restrict__ off, const float* __restrict__ agg,
    const float* __restrict__ l2w, const float* __restrict__ l2b,
    const float* __restrict__ lw, const float* __restrict__ lb,
    float* __restrict__ out, int N) {
    __shared__ float rows[32][HIDDEN];
    __shared__ float dinv[32];
    const int n0 = blockIdx.x * 32;
    const int tid = threadIdx.x;

    if (tid < 32) {
        int n = n0 + tid;
        float d = 1.0f;
        if (n < N) d = fmaxf((float)(off[n + 1] - off[n]), 1.0f);
        dinv[tid] = 1.0f / d;
    }

    const float4* ag = (const float4*)(agg + (size_t)n0 * HIDDEN);
    float4 v[4];
#pragma unroll
    for (int i = 0; i < 4; ++i) {
        int fi = i * 256 + tid;
        int nr = n0 + (fi >> 5);
        v[i] = (nr < N) ? ag[fi] : make_float4(0.f, 0.f, 0.f, 0.f);
    }
    __syncthreads();   // dinv ready
#pragma unroll
    for (int i = 0; i < 4; ++i) {
        int fi = i * 256 + tid;
        float s = dinv[fi >> 5];
        float4 r;
        r.x = v[i].x * s; r.y = v[i].y * s; r.z = v[i].z * s; r.w = v[i].w * s;
        ((float4*)rows)[fi] = r;
    }
    __syncthreads();

    const int f = tid & 127;
    const int ng = tid >> 7;

    // GEMM1: lin2 + bias, silu
    float acc[16];
    {
        float bb = l2b[f];
#pragma unroll
        for (int j = 0; j < 16; ++j) acc[j] = bb;
    }
    for (int k4 = 0; k4 < HIDDEN / 4; ++k4) {
        const float* wp = l2w + k4 * 4 * HIDDEN + f;
        float w0 = wp[0], w1 = wp[HIDDEN], w2 = wp[2 * HIDDEN], w3 = wp[3 * HIDDEN];
#pragma unroll
        for (int j = 0; j < 16; ++j) {
            float4 r = *(const float4*)&rows[ng * 16 + j][k4 * 4];
            acc[j] += r.x * w0 + r.y * w1 + r.z * w2 + r.w * w3;
        }
    }
#pragma unroll
    for (int j = 0; j < 16; ++j) acc[j] = silu(acc[j]);
    __syncthreads();   // all GEMM1 reads of rows done
#pragma unroll
    for (int j = 0; j < 16; ++j) rows[ng * 16 + j][f] = acc[j];
    __syncthreads();

    // GEMM2: lin + bias
    float acc2[16];
    {
        float bb = lb[f];
#pragma unroll
        for (int j = 0; j < 16; ++j) acc2[j] = bb;
    }
    for (int k4 = 0; k4 < HIDDEN / 4; ++k4) {
        const float* wp = lw + k4 * 4 * HIDDEN + f;
        float w0 = wp[0], w1 = wp[HIDDEN], w2 = wp[2 * HIDDEN], w3 = wp[3 * HIDDEN];
#pragma unroll
        for (int j = 0; j < 16; ++j) {
            float4 r = *(const float4*)&rows[ng * 16 + j][k4 * 4];
            acc2[j] += r.x * w0 + r.y * w1 + r.z * w2 + r.w * w3;
        }
    }
#pragma unroll
    for (int j = 0; j < 16; ++j) {
        int n = n0 + ng * 16 + j;
        if (n < N) out[(size_t)n * HIDDEN + f] = acc2[j];
    }
}

// ---------------------------------------------------------------------------
static inline char* align_up(char* p, size_t a) {
    return (char*)(((uintptr_t)p + a - 1) & ~(uintptr_t)(a - 1));
}

extern "C" void kernel_launch(void* const* d_in, const int* in_sizes, int n_in,
                              void* d_out, int out_size, void* d_ws, size_t ws_size,
                              hipStream_t stream) {
    const float* x   = (const float*)d_in[0];
    const int*   ei  = (const int*)d_in[1];
    const float* ew  = (const float*)d_in[2];
    const float* ea  = (const float*)d_in[3];
    const float* w1  = (const float*)d_in[4];
    const float* b1  = (const float*)d_in[5];
    const float* w2  = (const float*)d_in[6];
    const float* b2  = (const float*)d_in[7];
    const float* l1w = (const float*)d_in[8];
    const float* l2w = (const float*)d_in[9];
    const float* l2b = (const float*)d_in[10];
    const float* lw  = (const float*)d_in[11];
    const float* lb  = (const float*)d_in[12];

    const int N = in_sizes[0] / HIDDEN;   // 100000
    const int E = in_sizes[2];            // 1600000
    const int* src = ei;
    const int* dst = ei + E;

    const int NB = (N + 1023) / 1024;     // scan blocks

    // workspace carve-up (256B aligned)
    char* p = (char*)d_ws;
    float* xf = (float*)p;        p = align_up(p + (size_t)N * HIDDEN * 4, 256);
    short* w1f = (short*)p;       p = align_up(p + HIDDEN * NRBF * 2, 256);
    short* w2f = (short*)p;       p = align_up(p + HIDDEN * HIDDEN * 2, 256);
    int* counts = (int*)p;        p = align_up(p + (size_t)N * 4, 256);
    int* off = (int*)p;           p = align_up(p + (size_t)(N + 1) * 4, 256);
    int* cursor = (int*)p;        p = align_up(p + (size_t)N * 4, 256);
    int* bsums = (int*)p;         p = align_up(p + (size_t)NB * 4, 256);
    int* csr = (int*)p;           p = align_up(p + (size_t)E * 4, 256);
    float* agg = (float*)p;       // N*128 fp32 = 51.2 MB

    hipMemsetAsync(counts, 0, (size_t)N * sizeof(int), stream);
    hipMemsetAsync(agg, 0, (size_t)N * HIDDEN * sizeof(float), stream);

    conv_weights<<<(HIDDEN * HIDDEN + 255) / 256, 256, 0, stream>>>(w1, w2, w1f, w2f);

    gemm32<<<(N + 31) / 32, 256, 0, stream>>>(x, l1w, xf, N);

    hist_kernel<<<(E + 255) / 256, 256, 0, stream>>>(dst, counts, E);
    scan_part1<<<NB, 256, 0, stream>>>(counts, bsums, N);
    scan_part2<<<1, 1024, 0, stream>>>(bsums, NB, off + N);
    scan_part3<<<NB, 256, 0, stream>>>(counts, bsums, off, cursor, N);
    fill_kernel<<<(E + 255) / 256, 256, 0, stream>>>(dst, cursor, csr, E);

    msg_mfma<<<(E + 127) / 128, 256, 0, stream>>>(
        csr, src, dst, ew, ea, w1f, b1, w2f, b2, xf, agg, E);

    tail32<<<(N + 31) / 32, 256, 0, stream>>>(
        off, agg, l2w, l2b, lw, lb, (float*)d_out, N);
}